// Round 1
// baseline (266.019 us; speedup 1.0000x reference)
//
#include <hip/hip_runtime.h>

#define L2048 2048
#define CHUNKS 32          // L / 64 lanes
#define K_SEL 64
#define R0_C 4.0f
#define INV_DELTA 5.0f     // 1 / (0.2 + 1e-12)
#define WALL_C 10.0f
#define BIGV 1e12f
#define D2CUT 100.0f       // R_CUT^2

__global__ __launch_bounds__(256) void rep_energy_kernel(const float* __restrict__ R,
                                                         float* __restrict__ out) {
    const int wave = threadIdx.x >> 6;
    const int lane = threadIdx.x & 63;
    const int row  = blockIdx.x * 4 + wave;
    const int b = row >> 11;           // / 2048
    const int i = row & (L2048 - 1);   // % 2048
    const float* Rb = R + (size_t)b * (L2048 * 3);

    const float xi = Rb[i * 3 + 0];
    const float yi = Rb[i * 3 + 1];
    const float zi = Rb[i * 3 + 2];

    // ---- pass 1: distances into 32 statically-indexed registers ----
    float d2v[CHUNKS];
    int cnt100 = 0;
    #pragma unroll
    for (int c = 0; c < CHUNKS; ++c) {
        const int j = c * 64 + lane;
        const float xj = Rb[j * 3 + 0];
        const float yj = Rb[j * 3 + 1];
        const float zj = Rb[j * 3 + 2];
        const float dx = xj - xi, dy = yj - yi, dz = zj - zi;
        float d2 = dx * dx;
        d2 = fmaf(dy, dy, d2);
        d2 = fmaf(dz, dz, d2);
        const int dj = j - i;
        if (dj >= -1 && dj <= 1) d2 = BIGV;   // exclude |i-j| < 2
        d2v[c] = d2;
        cnt100 += (d2 <= D2CUT) ? 1 : 0;
    }
    #pragma unroll
    for (int off = 32; off > 0; off >>= 1) cnt100 += __shfl_xor(cnt100, off, 64);

    // ---- pass 2: binary search for the 64-th smallest d2 (only if needed) ----
    float thr = D2CUT;
    if (cnt100 > K_SEL) {
        float lo = 0.0f, hi = D2CUT;
        for (int it = 0; it < 14; ++it) {
            const float mid = 0.5f * (lo + hi);
            int c = 0;
            #pragma unroll
            for (int k = 0; k < CHUNKS; ++k) c += (d2v[k] <= mid) ? 1 : 0;
            #pragma unroll
            for (int off = 32; off > 0; off >>= 1) c += __shfl_xor(c, off, 64);
            if (c >= K_SEL) hi = mid; else lo = mid;   // wave-uniform
        }
        thr = hi;   // count(<= thr) >= 64; extras live in a 6e-3-wide d2 window
    }

    // ---- pass 3: predicated f(r) accumulation ----
    float acc = 0.0f;
    #pragma unroll
    for (int k = 0; k < CHUNKS; ++k) {
        const float v = d2v[k];
        if (v <= thr) {
            const float r = sqrtf(v);
            const float x = (R0_C - r) * INV_DELTA;
            // numerically-stable softplus
            const float sp = fmaxf(x, 0.0f) + log1pf(__expf(-fabsf(x)));
            float t = (r - 8.0f) * 0.5f;
            t = fminf(fmaxf(t, 0.0f), 1.0f);
            const float sw = 1.0f - t * t * (3.0f - 2.0f * t);
            acc += WALL_C * sp * sw;
        }
    }
    #pragma unroll
    for (int off = 32; off > 0; off >>= 1) acc += __shfl_xor(acc, off, 64);

    if (lane == 0) atomicAdd(&out[b], acc);
}

extern "C" void kernel_launch(void* const* d_in, const int* in_sizes, int n_in,
                              void* d_out, int out_size, void* d_ws, size_t ws_size,
                              hipStream_t stream) {
    (void)n_in; (void)d_ws; (void)ws_size;
    const float* R = (const float*)d_in[0];
    float* out = (float*)d_out;

    hipMemsetAsync(out, 0, (size_t)out_size * sizeof(float), stream);

    const int B = in_sizes[0] / (L2048 * 3);
    const int rows = B * L2048;
    rep_energy_kernel<<<rows / 4, 256, 0, stream>>>(R, out);
}

// Round 3
// 223.626 us; speedup vs baseline: 1.1896x; 1.1896x over previous
//
#include <hip/hip_runtime.h>

#define L2048 2048
#define CHUNKS 32          // L / 64 lanes
#define BIGV 1e12f

// f(r) = WALL * softplus((R0-r)/DELTA) * smoothstep_down(r; 8, 10)
// softplus(x) = ln2 * log2(1 + exp2(x*log2e));  x = (4-r)*5
// exp2 argument: (20 - 5r) * log2e = 28.8539008 - 7.2134752*r
// Final scale WALL*ln2 = 6.93147181 applied once per wave.

__global__ __launch_bounds__(256) void rep_energy_kernel(const float* __restrict__ R,
                                                         float* __restrict__ out) {
    const int wave = threadIdx.x >> 6;
    const int lane = threadIdx.x & 63;
    const int row  = blockIdx.x * 4 + wave;
    const int b = row >> 11;           // / 2048
    const int i = row & (L2048 - 1);   // % 2048
    const float* Rb = R + (size_t)b * (L2048 * 3);

    const float xi = Rb[i * 3 + 0];
    const float yi = Rb[i * 3 + 1];
    const float zi = Rb[i * 3 + 2];

    float acc = 0.0f;
    #pragma unroll 8
    for (int c = 0; c < CHUNKS; ++c) {
        const int j = c * 64 + lane;
        const float xj = Rb[j * 3 + 0];
        const float yj = Rb[j * 3 + 1];
        const float zj = Rb[j * 3 + 2];
        const float dx = xj - xi, dy = yj - yi, dz = zj - zi;
        float d2 = dx * dx;
        d2 = fmaf(dy, dy, d2);
        d2 = fmaf(dz, dz, d2);
        // exclude |i-j| < 2 arithmetically: BIG distance -> f == 0 exactly
        if ((unsigned)(j - i + 1) <= 2u) d2 = BIGV;

        const float r = sqrtf(d2);
        // softplus((4-r)*5) / ln2  == log2(1 + exp2(28.8539 - 7.21348*r))
        const float e  = __builtin_amdgcn_exp2f(fmaf(r, -7.2134752f, 28.8539008f)); // v_exp_f32
        const float lg = __builtin_amdgcn_logf(1.0f + e);   // v_log_f32 == log2; 0 for far pairs
        // smoothstep down from 1 at r=8 to exactly 0 at r>=10
        float t = fmaf(r, 0.5f, -4.0f);
        t = fminf(fmaxf(t, 0.0f), 1.0f);
        const float sw = fmaf(-t * t, fmaf(-2.0f, t, 3.0f), 1.0f);
        acc = fmaf(lg, sw, acc);
    }

    #pragma unroll
    for (int off = 32; off > 0; off >>= 1) acc += __shfl_xor(acc, off, 64);

    if (lane == 0) atomicAdd(&out[b], acc * 6.93147181f);  // WALL * ln2
}

extern "C" void kernel_launch(void* const* d_in, const int* in_sizes, int n_in,
                              void* d_out, int out_size, void* d_ws, size_t ws_size,
                              hipStream_t stream) {
    (void)n_in; (void)d_ws; (void)ws_size;
    const float* R = (const float*)d_in[0];
    float* out = (float*)d_out;

    (void)hipMemsetAsync(out, 0, (size_t)out_size * sizeof(float), stream);

    const int B = in_sizes[0] / (L2048 * 3);
    const int rows = B * L2048;
    rep_energy_kernel<<<rows / 4, 256, 0, stream>>>(R, out);
}

// Round 4
// 25.334 us; speedup vs baseline: 10.5006x; 8.8272x over previous
//
#include <hip/hip_runtime.h>

#define L2048 2048
#define BIGV 1e12f

// f(r) = WALL * softplus((R0-r)/DELTA) * smoothstep_down(r; 8, 10)
// softplus(x) = ln2 * log2(1 + exp2(x*log2e));  x = (4-r)*5
// exp2 argument: (20 - 5r) * log2e = 28.8539008 - 7.2134752*r
// Triangular (j >= i+2) counted once -> final scale 2 * WALL * ln2.

__device__ __forceinline__ float pair_f(float d2) {
    const float r  = sqrtf(d2);
    const float e  = __builtin_amdgcn_exp2f(fmaf(r, -7.2134752f, 28.8539008f)); // v_exp_f32
    const float lg = __builtin_amdgcn_logf(1.0f + e);   // v_log_f32 == log2; 0 for far pairs
    float t = fmaf(r, 0.5f, -4.0f);                      // smoothstep 1@r=8 -> 0@r>=10
    t = fminf(fmaxf(t, 0.0f), 1.0f);
    const float sw = fmaf(-t * t, fmaf(-2.0f, t, 3.0f), 1.0f);
    return lg * sw;
}

__global__ __launch_bounds__(256) void pair_energy_kernel(const float* __restrict__ R,
                                                          float* __restrict__ ws) {
    const int wave = threadIdx.x >> 6;
    const int lane = threadIdx.x & 63;
    const int unit = blockIdx.x * 4 + wave;   // 1024 units per batch
    const int b = unit >> 10;
    const int u = unit & 1023;                // u==1023 is a no-op unit
    const float* Rb = R + (size_t)b * (L2048 * 3);

    float acc = 0.0f;

    if (u < 1023) {
        // ---- row A: i = u, j in [u+2, 2047] (nA = 2046-u pairs) ----
        {
            const int i  = u;
            const float xi = Rb[i * 3 + 0];
            const float yi = Rb[i * 3 + 1];
            const float zi = Rb[i * 3 + 2];
            const int j0 = i + 2;
            const int nA = 2046 - u;
            const int chunks = (nA + 63) >> 6;
            #pragma unroll 4
            for (int c = 0; c < chunks; ++c) {
                const int j  = j0 + c * 64 + lane;
                const int jj = (j < L2048) ? j : (L2048 - 1);
                const float xj = Rb[jj * 3 + 0];
                const float yj = Rb[jj * 3 + 1];
                const float zj = Rb[jj * 3 + 2];
                const float dx = xj - xi, dy = yj - yi, dz = zj - zi;
                float d2 = dx * dx;
                d2 = fmaf(dy, dy, d2);
                d2 = fmaf(dz, dz, d2);
                if (j >= L2048) d2 = BIGV;   // tail mask -> f == 0 arithmetically
                acc += pair_f(d2);
            }
        }
        // ---- row B: i2 = 2045-u, j in [2047-u, 2047] (nB = u+1 pairs) ----
        {
            const int i2 = 2045 - u;
            const float xi = Rb[i2 * 3 + 0];
            const float yi = Rb[i2 * 3 + 1];
            const float zi = Rb[i2 * 3 + 2];
            const int j0 = i2 + 2;
            const int nB = u + 1;
            const int chunks = (nB + 63) >> 6;
            #pragma unroll 4
            for (int c = 0; c < chunks; ++c) {
                const int j  = j0 + c * 64 + lane;
                const int jj = (j < L2048) ? j : (L2048 - 1);
                const float xj = Rb[jj * 3 + 0];
                const float yj = Rb[jj * 3 + 1];
                const float zj = Rb[jj * 3 + 2];
                const float dx = xj - xi, dy = yj - yi, dz = zj - zi;
                float d2 = dx * dx;
                d2 = fmaf(dy, dy, d2);
                d2 = fmaf(dz, dz, d2);
                if (j >= L2048) d2 = BIGV;
                acc += pair_f(d2);
            }
        }
    }

    #pragma unroll
    for (int off = 32; off > 0; off >>= 1) acc += __shfl_xor(acc, off, 64);

    __shared__ float sp[4];
    if (lane == 0) sp[wave] = acc;
    __syncthreads();
    if (threadIdx.x == 0)
        ws[blockIdx.x] = sp[0] + sp[1] + sp[2] + sp[3];   // plain store, no atomics
}

__global__ __launch_bounds__(256) void reduce_kernel(const float* __restrict__ ws,
                                                     float* __restrict__ out) {
    const int wave = threadIdx.x >> 6;
    const int lane = threadIdx.x & 63;
    float v = ws[blockIdx.x * 256 + threadIdx.x];
    #pragma unroll
    for (int off = 32; off > 0; off >>= 1) v += __shfl_xor(v, off, 64);
    __shared__ float sp[4];
    if (lane == 0) sp[wave] = v;
    __syncthreads();
    if (threadIdx.x == 0)
        out[blockIdx.x] = (sp[0] + sp[1] + sp[2] + sp[3]) * 13.86294361f; // 2*WALL*ln2
}

extern "C" void kernel_launch(void* const* d_in, const int* in_sizes, int n_in,
                              void* d_out, int out_size, void* d_ws, size_t ws_size,
                              hipStream_t stream) {
    (void)n_in; (void)out_size; (void)ws_size;
    const float* R = (const float*)d_in[0];
    float* out = (float*)d_out;
    float* ws  = (float*)d_ws;

    const int B = in_sizes[0] / (L2048 * 3);
    pair_energy_kernel<<<B * 256, 256, 0, stream>>>(R, ws);   // 1024 row-pair units / batch
    reduce_kernel<<<B, 256, 0, stream>>>(ws, out);            // 256 partials / batch
}